// Round 15
// baseline (48.990 us; speedup 1.0000x reference)
//
#include <hip/hip_runtime.h>
#include <hip/hip_fp16.h>
#include <hip/hip_bf16.h>

#define PP 7
#define SR 2
#define HH 128
#define WW 128
#define CC 256
#define PLANE (HH * WW)
#define MAXB 8
#define SLOT_BYTES 32768            // 128x128 bf16
#define WY_BASE (8 * SLOT_BYTES)    // 8 slots of WX, then 8 of WY
#define TAB_OFF (2 * WY_BASE)       // 524288
// ws: [0,256K) WX slots: [r][x] bf16 rows (256B). [256K,512K) WY slots: [y][r].
// tab ints at 512K: [0..7] imgStart, [8..15] tileCnt, [16..23] tileBase, [24..31] cnt

typedef unsigned int uint;
typedef short bf16x8 __attribute__((ext_vector_type(8)));
typedef float f32x16 __attribute__((ext_vector_type(16)));

__device__ __forceinline__ uint pkbf(float a, float b) {
  __hip_bfloat16 ha = __float2bfloat16(a), hb = __float2bfloat16(b);
  return (uint)*(unsigned short*)&ha | ((uint)*(unsigned short*)&hb << 16);
}

// ---------- setup: per-image counts / tile bases ----------
__global__ __launch_bounds__(64) void setup_kernel(
    const float* __restrict__ rois, unsigned char* wsb, int N, int B) {
  __shared__ int c[MAXB];
  const int t = threadIdx.x;
  if (t < MAXB) c[t] = 0;
  __syncthreads();
  for (int j = t; j < N; j += 64) atomicAdd(&c[(int)rois[j * 6]], 1);
  __syncthreads();
  if (t == 0) {
    int* tab = (int*)(wsb + TAB_OFF);
    int s = 0, tb = 0;
    for (int i = 0; i < B; ++i) {
      tab[i] = s; tab[24 + i] = c[i];
      const int tc = (c[i] + 127) >> 7;
      tab[8 + i] = tc; tab[16 + i] = tb;
      s += c[i]; tb += tc;
    }
  }
}

// ---------- meta: dense bf16 WX row + WY column per ROI ----------
__global__ __launch_bounds__(64) void roi_meta_kernel(
    const float* __restrict__ rois, unsigned char* wsb,
    float* __restrict__ out, int N) {
  const int roi = blockIdx.x;
  const int lane = threadIdx.x;

  __shared__ float WXs[WW], WYs[HH];
  WXs[lane] = 0.f; WXs[lane + 64] = 0.f;
  WYs[lane] = 0.f; WYs[lane + 64] = 0.f;
  __syncthreads();

  const float bf = rois[roi * 6 + 0];
  const float cx = rois[roi * 6 + 2];
  const float cy = rois[roi * 6 + 3];
  const float w_ = rois[roi * 6 + 4];
  const float h_ = rois[roi * 6 + 5];

  // f16 round-trip, contraction-free (match jnp float16 cast semantics)
  const float x1 = __half2float(__float2half(
      __fmul_rn(__fsub_rn(cx, __fmul_rn(0.5f, w_)), 128.0f)));
  const float y1 = __half2float(__float2half(
      __fmul_rn(__fsub_rn(cy, __fmul_rn(0.5f, h_)), 128.0f)));
  const float x2 = __half2float(__float2half(
      __fmul_rn(__fadd_rn(cx, __fmul_rn(0.5f, w_)), 128.0f)));
  const float y2 = __half2float(__float2half(
      __fmul_rn(__fadd_rn(cy, __fmul_rn(0.5f, h_)), 128.0f)));

  const float sx = fmaxf(__fsub_rn(x2, x1), 1.0f) / 7.0f;
  const float sy = fmaxf(__fsub_rn(y2, y1), 1.0f) / 7.0f;

  if (lane < 2 * PP * SR) {
    const int isX = lane >= PP * SR;
    const int i = lane - isX * PP * SR;          // 0..13
    const float off = (float)(i >> 1) + ((float)(i & 1) + 0.5f) * 0.5f;
    const float pos = __fadd_rn(isX ? x1 : y1, __fmul_rn(off, isX ? sx : sy));
    if (pos > -1.0f && pos < 128.0f) {
      const float pc = fminf(fmaxf(pos, 0.0f), 127.0f);
      const int p0 = (int)floorf(pc);
      const int p1 = min(p0 + 1, 127);
      const float l = pc - (float)p0;
      float* Warr = isX ? WXs : WYs;
      atomicAdd(&Warr[p0], 1.0f - l);
      atomicAdd(&Warr[p1], l);
    }
  }
  __syncthreads();

  const int* tab = (const int*)(wsb + TAB_OFF);
  const int img = (int)bf;
  const int rl = roi - tab[img];
  const int slot = tab[16 + img] + (rl >> 7);
  const int col = rl & 127;

  // WX row (coalesced u32 per lane)
  *(uint*)(wsb + (size_t)slot * SLOT_BYTES + col * 256 + lane * 4) =
      pkbf(WXs[2 * lane], WXs[2 * lane + 1]);
  // WY column (two u16 per lane)
  __hip_bfloat16 h0 = __float2bfloat16(WYs[lane]);
  __hip_bfloat16 h1 = __float2bfloat16(WYs[lane + 64]);
  unsigned char* wyb = wsb + WY_BASE + (size_t)slot * SLOT_BYTES + col * 2;
  *(unsigned short*)(wyb + lane * 256) = *(unsigned short*)&h0;
  *(unsigned short*)(wyb + (lane + 64) * 256) = *(unsigned short*)&h1;

  if (lane == 0) out[(size_t)N * CC + roi] = rois[roi * 6 + 1];  // gt
}

// ---------- GEMM: M1 = F_c * WX^T (MFMA), out = diag(WY^T * M1) ----------
__global__ __launch_bounds__(256, 4) void roi_gemm_kernel(
    const float* __restrict__ fm, const unsigned char* __restrict__ wsb,
    float* __restrict__ out, int N) {
  const int bid = blockIdx.x;
  const int ch = bid & (CC - 1);
  const int img = bid >> 8;
  const int t = threadIdx.x, wave = t >> 6, lane = t & 63;

  const int* tab = (const int*)(wsb + TAB_OFF);
  const int tcnt = tab[8 + img];
  if (tcnt == 0) return;
  const int istart = tab[img], Rimg = tab[24 + img], tbase = tab[16 + img];

  __shared__ unsigned char A[32768];     // [y][x] bf16, 256B rows, XOR-swizzled
  __shared__ float partial[4][128];

  // stage plane fp32 -> bf16 (swizzle: 16B chunk index ^= row&7)
  const float* pb = fm + ((size_t)img * CC + ch) * PLANE;
  #pragma unroll
  for (int k = 0; k < 8; ++k) {
    const int cid = k * 256 + t;                 // 8-float chunk, 0..2047
    const float4 v0 = *(const float4*)(pb + (size_t)cid * 8);
    const float4 v1 = *(const float4*)(pb + (size_t)cid * 8 + 4);
    const int row = cid >> 4, x8 = cid & 15;
    const int boff = (row << 8) | ((x8 ^ (row & 7)) << 4);
    uint4 u;
    u.x = pkbf(v0.x, v0.y); u.y = pkbf(v0.z, v0.w);
    u.z = pkbf(v1.x, v1.y); u.w = pkbf(v1.z, v1.w);
    *(uint4*)(A + boff) = u;
  }
  __syncthreads();

  const int m0 = wave * 32;
  const int arow = m0 + (lane & 31);
  const int ar7 = arow & 7;
  const unsigned char* Arow = A + (arow << 8);
  const int ahalf = lane >> 5;

  for (int ti = 0; ti < tcnt; ++ti) {
    const unsigned char* BX = wsb + (size_t)(tbase + ti) * SLOT_BYTES;
    const unsigned char* BY = wsb + WY_BASE + (size_t)(tbase + ti) * SLOT_BYTES;
    const unsigned char* Bl = BX + (lane & 31) * 256 + ahalf * 16;

    f32x16 ac0 = {}, ac1 = {}, ac2 = {}, ac3 = {};

    auto ldA = [&](int ks) -> bf16x8 {
      const int idx = (ahalf + 2 * ks) ^ ar7;
      return *(const bf16x8*)(Arow + (idx << 4));
    };
    auto ldB = [&](int ks, int ni) -> bf16x8 {
      return *(const bf16x8*)(Bl + ni * (32 * 256) + ks * 32);
    };

    bf16x8 a = ldA(0);
    bf16x8 b0 = ldB(0, 0), b1 = ldB(0, 1), b2 = ldB(0, 2), b3 = ldB(0, 3);
    #pragma unroll
    for (int ks = 0; ks < 8; ++ks) {
      bf16x8 an{}, bn0{}, bn1{}, bn2{}, bn3{};
      if (ks < 7) {
        an = ldA(ks + 1);
        bn0 = ldB(ks + 1, 0); bn1 = ldB(ks + 1, 1);
        bn2 = ldB(ks + 1, 2); bn3 = ldB(ks + 1, 3);
      }
      ac0 = __builtin_amdgcn_mfma_f32_32x32x16_bf16(a, b0, ac0, 0, 0, 0);
      ac1 = __builtin_amdgcn_mfma_f32_32x32x16_bf16(a, b1, ac1, 0, 0, 0);
      ac2 = __builtin_amdgcn_mfma_f32_32x32x16_bf16(a, b2, ac2, 0, 0, 0);
      ac3 = __builtin_amdgcn_mfma_f32_32x32x16_bf16(a, b3, ac3, 0, 0, 0);
      a = an; b0 = bn0; b1 = bn1; b2 = bn2; b3 = bn3;
    }

    // stage 2: out[r] = sum_y WY[y][r] * M1[y][r]  (C/D: col=lane&31, row pat)
    #pragma unroll
    for (int ni = 0; ni < 4; ++ni) {
      const f32x16 acc = ni == 0 ? ac0 : ni == 1 ? ac1 : ni == 2 ? ac2 : ac3;
      float p = 0.f;
      #pragma unroll
      for (int j = 0; j < 16; ++j) {
        const int y = m0 + (j & 3) + 8 * (j >> 2) + 4 * ahalf;
        const unsigned short wy =
            *(const unsigned short*)(BY + y * 256 + (ni * 32 + (lane & 31)) * 2);
        p = fmaf(__uint_as_float((uint)wy << 16), acc[j], p);
      }
      p += __shfl_xor(p, 32, 64);
      if (lane < 32) partial[wave][ni * 32 + lane] = p;
    }
    __syncthreads();
    if (t < 128) {
      const int rl = ti * 128 + t;
      if (rl < Rimg) {
        const float s = partial[0][t] + partial[1][t] + partial[2][t] + partial[3][t];
        out[(size_t)(istart + rl) * CC + ch] = s * (1.0f / 196.0f);
      }
    }
    __syncthreads();
  }
}

extern "C" void kernel_launch(void* const* d_in, const int* in_sizes, int n_in,
                              void* d_out, int out_size, void* d_ws, size_t ws_size,
                              hipStream_t stream) {
  const float* fm   = (const float*)d_in[0];
  const float* rois = (const float*)d_in[1];
  float* out = (float*)d_out;
  unsigned char* wsb = (unsigned char*)d_ws;
  const int N = in_sizes[1] / 6;
  const int B = in_sizes[0] / (CC * PLANE);
  hipMemsetAsync(wsb, 0, TAB_OFF + 128, stream);
  setup_kernel<<<1, 64, 0, stream>>>(rois, wsb, N, B);
  roi_meta_kernel<<<N, 64, 0, stream>>>(rois, wsb, out, N);
  roi_gemm_kernel<<<B * CC, 256, 0, stream>>>(fm, wsb, out, N);
}

// Round 16
// 31.791 us; speedup vs baseline: 1.5410x; 1.5410x over previous
//
#include <hip/hip_runtime.h>
#include <hip/hip_fp16.h>
#include <hip/hip_bf16.h>

#define PP 7
#define SR 2
#define HH 128
#define WW 128
#define CC 256
#define PLANE (HH * WW)
#define MAXB 8
#define SLOT_BYTES 32768            // 128x128 bf16
#define WY_BASE (8 * SLOT_BYTES)    // 8 slots of WX, then 8 of WY
#define TAB_OFF (2 * WY_BASE)       // 524288
// ws: [0,256K) WX slots: [r][chunk^(r&7)] bf16 (PRE-SWIZZLED rows, 256B).
//     [256K,512K) WY slots: [y][r] bf16 rows (256B).
// tab ints at 512K: [0..7] imgStart, [8..15] tileCnt, [16..23] tileBase, [24..31] cnt

typedef unsigned int uint;
typedef short bf16x8 __attribute__((ext_vector_type(8)));
typedef float f32x16 __attribute__((ext_vector_type(16)));

typedef const __attribute__((address_space(1))) void g_void;
typedef __attribute__((address_space(3))) void l_void;

__device__ __forceinline__ void gload_lds16(const void* g, void* lds_base) {
  __builtin_amdgcn_global_load_lds((g_void*)g, (l_void*)lds_base, 16, 0, 0);
}

__device__ __forceinline__ uint pkbf(float a, float b) {
  __hip_bfloat16 ha = __float2bfloat16(a), hb = __float2bfloat16(b);
  return (uint)*(unsigned short*)&ha | ((uint)*(unsigned short*)&hb << 16);
}

// ---------- setup: per-image counts / tile bases ----------
__global__ __launch_bounds__(64) void setup_kernel(
    const float* __restrict__ rois, unsigned char* wsb, int N, int B) {
  __shared__ int c[MAXB];
  const int t = threadIdx.x;
  if (t < MAXB) c[t] = 0;
  __syncthreads();
  for (int j = t; j < N; j += 64) atomicAdd(&c[(int)rois[j * 6]], 1);
  __syncthreads();
  if (t == 0) {
    int* tab = (int*)(wsb + TAB_OFF);
    int s = 0, tb = 0;
    for (int i = 0; i < B; ++i) {
      tab[i] = s; tab[24 + i] = c[i];
      const int tc = (c[i] + 127) >> 7;
      tab[8 + i] = tc; tab[16 + i] = tb;
      s += c[i]; tb += tc;
    }
  }
}

// ---------- meta: dense bf16 WX row (pre-swizzled) + WY column per ROI ----------
__global__ __launch_bounds__(64) void roi_meta_kernel(
    const float* __restrict__ rois, unsigned char* wsb,
    float* __restrict__ out, int N) {
  const int roi = blockIdx.x;
  const int lane = threadIdx.x;

  __shared__ float WXs[WW], WYs[HH];
  WXs[lane] = 0.f; WXs[lane + 64] = 0.f;
  WYs[lane] = 0.f; WYs[lane + 64] = 0.f;
  __syncthreads();

  const float bf = rois[roi * 6 + 0];
  const float cx = rois[roi * 6 + 2];
  const float cy = rois[roi * 6 + 3];
  const float w_ = rois[roi * 6 + 4];
  const float h_ = rois[roi * 6 + 5];

  // f16 round-trip, contraction-free (match jnp float16 cast semantics)
  const float x1 = __half2float(__float2half(
      __fmul_rn(__fsub_rn(cx, __fmul_rn(0.5f, w_)), 128.0f)));
  const float y1 = __half2float(__float2half(
      __fmul_rn(__fsub_rn(cy, __fmul_rn(0.5f, h_)), 128.0f)));
  const float x2 = __half2float(__float2half(
      __fmul_rn(__fadd_rn(cx, __fmul_rn(0.5f, w_)), 128.0f)));
  const float y2 = __half2float(__float2half(
      __fmul_rn(__fadd_rn(cy, __fmul_rn(0.5f, h_)), 128.0f)));

  const float sx = fmaxf(__fsub_rn(x2, x1), 1.0f) / 7.0f;
  const float sy = fmaxf(__fsub_rn(y2, y1), 1.0f) / 7.0f;

  if (lane < 2 * PP * SR) {
    const int isX = lane >= PP * SR;
    const int i = lane - isX * PP * SR;          // 0..13
    const float off = (float)(i >> 1) + ((float)(i & 1) + 0.5f) * 0.5f;
    const float pos = __fadd_rn(isX ? x1 : y1, __fmul_rn(off, isX ? sx : sy));
    if (pos > -1.0f && pos < 128.0f) {
      const float pc = fminf(fmaxf(pos, 0.0f), 127.0f);
      const int p0 = (int)floorf(pc);
      const int p1 = min(p0 + 1, 127);
      const float l = pc - (float)p0;
      float* Warr = isX ? WXs : WYs;
      atomicAdd(&Warr[p0], 1.0f - l);
      atomicAdd(&Warr[p1], l);
    }
  }
  __syncthreads();

  const int* tab = (const int*)(wsb + TAB_OFF);
  const int img = (int)bf;
  const int rl = roi - tab[img];
  const int slot = tab[16 + img] + (rl >> 7);
  const int col = rl & 127;

  // WX row, PRE-SWIZZLED: 16B chunk (lane>>2) stored at chunk^(col&7)
  const int sw = ((((lane >> 2) ^ (col & 7)) << 4) | ((lane & 3) << 2));
  *(uint*)(wsb + (size_t)slot * SLOT_BYTES + col * 256 + sw) =
      pkbf(WXs[2 * lane], WXs[2 * lane + 1]);
  // WY column (two u16 per lane), layout [y][r]
  __hip_bfloat16 h0 = __float2bfloat16(WYs[lane]);
  __hip_bfloat16 h1 = __float2bfloat16(WYs[lane + 64]);
  unsigned char* wyb = wsb + WY_BASE + (size_t)slot * SLOT_BYTES + col * 2;
  *(unsigned short*)(wyb + lane * 256) = *(unsigned short*)&h0;
  *(unsigned short*)(wyb + (lane + 64) * 256) = *(unsigned short*)&h1;

  if (lane == 0) out[(size_t)N * CC + roi] = rois[roi * 6 + 1];  // gt
}

// ---------- GEMM: M1 = F_c * WX^T (MFMA), out = diag(WY^T * M1) ----------
__global__ __launch_bounds__(256, 2) void roi_gemm_kernel(
    const float* __restrict__ fm, const unsigned char* __restrict__ wsb,
    float* __restrict__ out, int N) {
  const int bid = blockIdx.x;
  const int ch = bid & (CC - 1);
  const int img = bid >> 8;
  const int t = threadIdx.x, wave = t >> 6, lane = t & 63;

  const int* tab = (const int*)(wsb + TAB_OFF);
  const int tcnt = tab[8 + img];
  if (tcnt == 0) return;
  const int istart = tab[img], Rimg = tab[24 + img], tbase = tab[16 + img];

  __shared__ unsigned char A[32768];     // plane [y][chunk^(y&7)] bf16
  __shared__ unsigned char BXl[32768];   // WX tile, same swizzle (linear copy)
  __shared__ float partial[4][128];

  // stage plane fp32 -> bf16 (swizzle: 16B chunk index ^= row&7)
  const float* pb = fm + ((size_t)img * CC + ch) * PLANE;
  #pragma unroll
  for (int k = 0; k < 8; ++k) {
    const int cid = k * 256 + t;                 // 8-float chunk, 0..2047
    const float4 v0 = *(const float4*)(pb + (size_t)cid * 8);
    const float4 v1 = *(const float4*)(pb + (size_t)cid * 8 + 4);
    const int row = cid >> 4, x8 = cid & 15;
    const int boff = (row << 8) | ((x8 ^ (row & 7)) << 4);
    uint4 u;
    u.x = pkbf(v0.x, v0.y); u.y = pkbf(v0.z, v0.w);
    u.z = pkbf(v1.x, v1.y); u.w = pkbf(v1.z, v1.w);
    *(uint4*)(A + boff) = u;
  }

  const int m0 = wave * 32;
  const int arow = m0 + (lane & 31);
  const int ar7 = arow & 7;
  const unsigned char* Arow = A + (arow << 8);
  const int ahalf = lane >> 5;
  const int r7 = lane & 7;

  for (int ti = 0; ti < tcnt; ++ti) {
    const unsigned char* BXg = wsb + (size_t)(tbase + ti) * SLOT_BYTES;
    const unsigned char* BY = wsb + WY_BASE + (size_t)(tbase + ti) * SLOT_BYTES;

    // stage WX tile: coalesced linear async copy (pre-swizzled in ws)
    #pragma unroll
    for (int k2 = 0; k2 < 8; ++k2)
      gload_lds16(BXg + k2 * 4096 + wave * 1024 + (lane << 4),
                  BXl + k2 * 4096 + wave * 1024);
    asm volatile("s_waitcnt vmcnt(0)" ::: "memory");
    __syncthreads();                    // A (ti==0) + BX staged

    f32x16 ac0 = {}, ac1 = {}, ac2 = {}, ac3 = {};

    auto ldA = [&](int ks) -> bf16x8 {
      const int idx = (ahalf + 2 * ks) ^ ar7;
      return *(const bf16x8*)(Arow + (idx << 4));
    };
    auto ldB = [&](int ks, int ni) -> bf16x8 {
      const int c = (2 * ks + ahalf) ^ r7;
      return *(const bf16x8*)(BXl + (((lane & 31) + 32 * ni) << 8) + (c << 4));
    };

    bf16x8 a = ldA(0);
    bf16x8 b0 = ldB(0, 0), b1 = ldB(0, 1), b2 = ldB(0, 2), b3 = ldB(0, 3);
    #pragma unroll
    for (int ks = 0; ks < 8; ++ks) {
      bf16x8 an{}, bn0{}, bn1{}, bn2{}, bn3{};
      if (ks < 7) {
        an = ldA(ks + 1);
        bn0 = ldB(ks + 1, 0); bn1 = ldB(ks + 1, 1);
        bn2 = ldB(ks + 1, 2); bn3 = ldB(ks + 1, 3);
      }
      ac0 = __builtin_amdgcn_mfma_f32_32x32x16_bf16(a, b0, ac0, 0, 0, 0);
      ac1 = __builtin_amdgcn_mfma_f32_32x32x16_bf16(a, b1, ac1, 0, 0, 0);
      ac2 = __builtin_amdgcn_mfma_f32_32x32x16_bf16(a, b2, ac2, 0, 0, 0);
      ac3 = __builtin_amdgcn_mfma_f32_32x32x16_bf16(a, b3, ac3, 0, 0, 0);
      a = an; b0 = bn0; b1 = bn1; b2 = bn2; b3 = bn3;
    }

    // stage 2: out[r] = sum_y WY[y][r] * M1[y][r]  (C/D: col=lane&31 = r)
    #pragma unroll
    for (int ni = 0; ni < 4; ++ni) {
      const f32x16 acc = ni == 0 ? ac0 : ni == 1 ? ac1 : ni == 2 ? ac2 : ac3;
      float p = 0.f;
      #pragma unroll
      for (int j = 0; j < 16; ++j) {
        const int y = m0 + (j & 3) + 8 * (j >> 2) + 4 * ahalf;
        const unsigned short wy =
            *(const unsigned short*)(BY + y * 256 + (ni * 32 + (lane & 31)) * 2);
        p = fmaf(__uint_as_float((uint)wy << 16), acc[j], p);
      }
      p += __shfl_xor(p, 32, 64);
      if (lane < 32) partial[wave][ni * 32 + lane] = p;
    }
    __syncthreads();
    if (t < 128) {
      const int rl = ti * 128 + t;
      if (rl < Rimg) {
        const float s = partial[0][t] + partial[1][t] + partial[2][t] + partial[3][t];
        out[(size_t)(istart + rl) * CC + ch] = s * (1.0f / 196.0f);
      }
    }
    __syncthreads();                    // partial consumed before next stage
  }
}

extern "C" void kernel_launch(void* const* d_in, const int* in_sizes, int n_in,
                              void* d_out, int out_size, void* d_ws, size_t ws_size,
                              hipStream_t stream) {
  const float* fm   = (const float*)d_in[0];
  const float* rois = (const float*)d_in[1];
  float* out = (float*)d_out;
  unsigned char* wsb = (unsigned char*)d_ws;
  const int N = in_sizes[1] / 6;
  const int B = in_sizes[0] / (CC * PLANE);
  setup_kernel<<<1, 64, 0, stream>>>(rois, wsb, N, B);
  roi_meta_kernel<<<N, 64, 0, stream>>>(rois, wsb, out, N);
  roi_gemm_kernel<<<B * CC, 256, 0, stream>>>(fm, wsb, out, N);
}